// Round 3
// baseline (1557.588 us; speedup 1.0000x reference)
//
#include <hip/hip_runtime.h>

// FP16(pulse bits, 16 floats of 0/1) -> FP8 E4M3 (pulse bits, 8 floats of 0/1).
// Purely memory-bound: 64 B in + 32 B out per item, 16.7M items -> 1.61 GB/call,
// roofline ~256 us at 6.3 TB/s.
//
// All-integer datapath: a 0.0f/1.0f float word's value bit is (w>>23)&1 (v_bfe),
// output pulse word is (0-bit)&0x3F800000 (no v_cvt). Branchless selects (random
// exponents make a 4-way if/else fully divergent per wave). Non-temporal
// loads/stores (native ext_vector_type — HIP's uint4 class is rejected by the
// builtin): both streams are touch-once; keep them out of L2.

typedef unsigned int u32;
typedef u32 u32x4 __attribute__((ext_vector_type(4)));

__global__ __launch_bounds__(256) void fp16_to_fp8_pulse_kernel(
    const u32x4* __restrict__ in,   // 4 x u32x4 per item
    u32x4* __restrict__ out,        // 2 x u32x4 per item
    int n_items)
{
    int i = blockIdx.x * blockDim.x + threadIdx.x;
    if (i >= n_items) return;

    const u32x4 v0 = __builtin_nontemporal_load(&in[4 * i + 0]);
    const u32x4 v1 = __builtin_nontemporal_load(&in[4 * i + 1]);
    const u32x4 v2 = __builtin_nontemporal_load(&in[4 * i + 2]);
    const u32x4 v3 = __builtin_nontemporal_load(&in[4 * i + 3]);

    // bit of a 0.0f / 1.0f IEEE word
#define BIT(w) (((w) >> 23) & 1u)
    const u32 s = BIT(v0.x);
    const u32 e = (BIT(v0.y) << 4) | (BIT(v0.z) << 3) | (BIT(v0.w) << 2) |
                  (BIT(v1.x) << 1) |  BIT(v1.y);
    const u32 m = (BIT(v1.z) << 9) | (BIT(v1.w) << 8) | (BIT(v2.x) << 7) |
                  (BIT(v2.y) << 6) | (BIT(v2.z) << 5) | (BIT(v2.w) << 4) |
                  (BIT(v3.x) << 3) | (BIT(v3.y) << 2) | (BIT(v3.z) << 1) |
                   BIT(v3.w);
#undef BIT

    // --- normal path: RNE(m >> 7), exponent bump on mantissa carry
    const u32 keep_n   = m >> 7;
    const u32 rbit_n   = (m >> 6) & 1u;
    const u32 sticky_n = (m & 63u) ? 1u : 0u;
    const u32 mant_r   = keep_n + (rbit_n & (sticky_n | (keep_n & 1u)));
    const u32 norm_e   = (e - 8u) + (mant_r >> 3);   // only selected when e >= 9
    const u32 norm_m   = mant_r & 7u;

    // --- subnormal path: RNE((1024 + m) >> clip(16-e, 8, 11))
    u32 k = 16u - e;                 // unsigned wrap for e>16 is clipped to 11
    k = k < 8u ? 8u : (k > 11u ? 11u : k);
    const u32 x        = 1024u + m;
    const u32 keep_s   = x >> k;
    const u32 rbit_s   = (x >> (k - 1u)) & 1u;
    const u32 sticky_s = (x & ((1u << (k - 1u)) - 1u)) ? 1u : 0u;
    const u32 m_sub    = keep_s + (rbit_s & (sticky_s | (keep_s & 1u)));
    const u32 sub_e    = m_sub >> 3;
    const u32 sub_m    = (m_sub >= 8u) ? 0u : m_sub;

    // --- branchless select (ovf | unf | subnormal | normal)
    const u32 out_e = (e > 22u) ? 15u : (e < 5u) ? 0u : (e <= 8u) ? sub_e : norm_e;
    const u32 out_m = (e > 22u) ? 6u  : (e < 5u) ? 0u : (e <= 8u) ? sub_m : norm_m;

    // pulse word: bit ? 1.0f : 0.0f, as integer
#define PULSE(b) ((0u - (b)) & 0x3F800000u)
    u32x4 o0, o1;
    o0.x = PULSE(s);
    o0.y = PULSE((out_e >> 3) & 1u);
    o0.z = PULSE((out_e >> 2) & 1u);
    o0.w = PULSE((out_e >> 1) & 1u);
    o1.x = PULSE(out_e & 1u);
    o1.y = PULSE((out_m >> 2) & 1u);
    o1.z = PULSE((out_m >> 1) & 1u);
    o1.w = PULSE(out_m & 1u);
#undef PULSE

    __builtin_nontemporal_store(o0, &out[2 * i + 0]);
    __builtin_nontemporal_store(o1, &out[2 * i + 1]);
}

extern "C" void kernel_launch(void* const* d_in, const int* in_sizes, int n_in,
                              void* d_out, int out_size, void* d_ws, size_t ws_size,
                              hipStream_t stream) {
    const u32x4* in = (const u32x4*)d_in[0];
    u32x4* out = (u32x4*)d_out;

    const int n_items = in_sizes[0] / 16;            // 4096*4096 = 16,777,216
    const int block = 256;
    const int grid = (n_items + block - 1) / block;  // 65536

    fp16_to_fp8_pulse_kernel<<<grid, block, 0, stream>>>(in, out, n_items);
}

// Round 4
// 1437.017 us; speedup vs baseline: 1.0839x; 1.0839x over previous
//
#include <hip/hip_runtime.h>

// FP16(pulse bits, 16 floats of 0/1) -> FP8 E4M3 (pulse bits, 8 floats of 0/1).
// Memory-bound: 1.074 GB in + 0.537 GB out per call, HBM floor ~256 us.
//
// Layout fix vs R1/R3: previously one thread consumed 64 contiguous bytes, so
// each vmem instruction was a wave-level stride-64 pattern (every cache line
// touched by 4 separate instructions, 16 useful B each). Now one thread = one
// uint4 (quarter item); lanes 4k..4k+3 hold parts 0..3 of item k. A 2-step
// __shfl_xor butterfly assembles the full 16-bit word in-register, every lane
// converts (redundant x4, VALU is ~free), and each lane stores its uint2 slice
// of the output. Input uint4 index == output uint2 index == global thread id:
// both streams perfectly lane-contiguous (16 B/lane load, 8 B/lane store).

typedef unsigned int u32;
typedef u32 u32x4 __attribute__((ext_vector_type(4)));
typedef u32 u32x2 __attribute__((ext_vector_type(2)));

__global__ __launch_bounds__(256) void fp16_to_fp8_pulse_kernel(
    const u32x4* __restrict__ in,   // one uint4 = 4 pulse bits (quarter item)
    u32x2* __restrict__ out,        // one uint2 = 2 output pulse words
    int n4)                          // total uint4 count = n_items * 4
{
    const int g = blockIdx.x * blockDim.x + threadIdx.x;
    if (g >= n4) return;

    const u32x4 v = in[g];
    const u32 p = (u32)(threadIdx.x & 3);   // part index within the item

    // pulse word (0.0f / 1.0f) -> bit
#define BIT(w) (((w) >> 23) & 1u)
    // part p covers bits (15-4p)..(12-4p), MSB first within the uint4
    const u32 nib = (BIT(v.x) << 3) | (BIT(v.y) << 2) | (BIT(v.z) << 1) | BIT(v.w);
#undef BIT

    // butterfly transpose within each 4-lane group: all lanes end with word16
    const u32 o1   = (u32)__shfl_xor((int)nib, 1);
    const u32 pair = (p & 1u) ? ((o1 << 4) | nib) : ((nib << 4) | o1);
    const u32 o2   = (u32)__shfl_xor((int)pair, 2);
    const u32 word = (p & 2u) ? ((o2 << 8) | pair) : ((pair << 8) | o2);

    const u32 s = word >> 15;
    const u32 e = (word >> 10) & 31u;
    const u32 m = word & 1023u;

    // --- normal path: RNE(m >> 7), exponent bump on mantissa carry
    const u32 keep_n   = m >> 7;
    const u32 rbit_n   = (m >> 6) & 1u;
    const u32 sticky_n = (m & 63u) ? 1u : 0u;
    const u32 mant_r   = keep_n + (rbit_n & (sticky_n | (keep_n & 1u)));
    const u32 norm_e   = (e - 8u) + (mant_r >> 3);   // only selected when e >= 9
    const u32 norm_m   = mant_r & 7u;

    // --- subnormal path: RNE((1024 + m) >> clip(16-e, 8, 11))
    u32 k = 16u - e;
    k = k < 8u ? 8u : (k > 11u ? 11u : k);
    const u32 x        = 1024u + m;
    const u32 keep_s   = x >> k;
    const u32 rbit_s   = (x >> (k - 1u)) & 1u;
    const u32 sticky_s = (x & ((1u << (k - 1u)) - 1u)) ? 1u : 0u;
    const u32 m_sub    = keep_s + (rbit_s & (sticky_s | (keep_s & 1u)));
    const u32 sub_e    = m_sub >> 3;
    const u32 sub_m    = (m_sub >= 8u) ? 0u : m_sub;

    // --- branchless select (ovf | unf | subnormal | normal)
    const u32 out_e = (e > 22u) ? 15u : (e < 5u) ? 0u : (e <= 8u) ? sub_e : norm_e;
    const u32 out_m = (e > 22u) ? 6u  : (e < 5u) ? 0u : (e <= 8u) ? sub_m : norm_m;

    // output byte, MSB first: [S, e3, e2, e1, e0, m2, m1, m0]
    const u32 obyte = (s << 7) | (out_e << 3) | out_m;

    // lane p stores output bits (7-2p) and (6-2p) as two pulse words
    const u32 hi = (obyte >> (7u - 2u * p)) & 1u;
    const u32 lo = (obyte >> (6u - 2u * p)) & 1u;

    u32x2 o;
    o.x = (0u - hi) & 0x3F800000u;
    o.y = (0u - lo) & 0x3F800000u;
    out[g] = o;
}

extern "C" void kernel_launch(void* const* d_in, const int* in_sizes, int n_in,
                              void* d_out, int out_size, void* d_ws, size_t ws_size,
                              hipStream_t stream) {
    const u32x4* in = (const u32x4*)d_in[0];
    u32x2* out = (u32x2*)d_out;

    const int n4 = in_sizes[0] / 4;                // 67,108,864 uint4s
    const int block = 256;
    const int grid = (n4 + block - 1) / block;     // 262,144 blocks

    fp16_to_fp8_pulse_kernel<<<grid, block, 0, stream>>>(in, out, n4);
}